// Round 13
// baseline (259.018 us; speedup 1.0000x reference)
//
#include <hip/hip_runtime.h>

#define T_LEN 100
#define H 32
#define L 6
#define NT 6          // 96 gate rows / 16
#define TPB 512       // 8 waves: SIMD s hosts waves {s, s+4}
#define BT 32         // two independent 16-batch groups per block
#define NPAIR 25      // four timesteps per barrier interval
#define NK (NPAIR + L - 1)   // 30 intervals, layer skew d = layer
#define S1 1.44269504088896f   // log2(e)

typedef float f32x4  __attribute__((ext_vector_type(4)));
typedef _Float16 f16x8 __attribute__((ext_vector_type(8)));

union FragU { f16x8 h; f32x4 f; unsigned int u[4]; };

__device__ inline unsigned short f2h(float f) {
    union { _Float16 h; unsigned short u; } v; v.h = (_Float16)f; return v.u;
}
__device__ inline float rcpa(float x)  { return __builtin_amdgcn_rcpf(x); }
__device__ inline float exp2b(float x) { return __builtin_amdgcn_exp2f(x); }

// pack f32 pair -> one u32 of 2 f16 (RTZ)
__device__ inline unsigned int pk16(float a, float b) {
    unsigned int h;
    asm("v_cvt_pkrtz_f16_f32 %0, %1, %2" : "=v"(h) : "v"(a), "v"(b));
    return h;
}

// ---- prep: pack weight A-fragments as f16 (matmul-operand quantization;
// the f32 recurrent state hp is never quantized), pre-scaled by -log2e /
// -2log2e, with kappa k-relabeling: hardware k-slot (gk*8+e) holds W column
// j = (e>>2)*16 + gk*4 + (e&3).  This makes MFMA C/D layout == B-frag layout.
__global__ void pack_frags(const float* __restrict__ Whh, const float* __restrict__ Wih,
                           unsigned short* __restrict__ WhFhi,
                           unsigned short* __restrict__ WiFhi)
{
    int tid = blockIdx.x * blockDim.x + threadIdx.x;
    const int NWH = L * NT * 64;          // 2304
    const int NWI = (L - 1) * NT * 64;    // 1920
    if (tid >= NWH + NWI) return;
    const float* src; unsigned short *dhi; int tile, lane;
    if (tid < NWH) {
        int l = tid / (NT * 64); int r = tid % (NT * 64); tile = r / 64; lane = r % 64;
        src = Whh + l * 96 * H;
        dhi = WhFhi + tid * 8;
    } else {
        int t2 = tid - NWH;
        int l = t2 / (NT * 64); int r = t2 % (NT * 64); tile = r / 64; lane = r % 64;
        src = Wih + l * 96 * H;           // W_ih[l] feeds layer l+1
        dhi = WiFhi + t2 * 8;
    }
    int row = tile * 16 + (lane & 15);
    int gk  = lane >> 4;
    float scale = (row < 64) ? -S1 : -2.0f * S1;
    unsigned short thi[8];
#pragma unroll
    for (int e = 0; e < 8; ++e) {
        int j = ((e >> 2) << 4) + (gk << 2) + (e & 3);   // kappa^-1
        thi[e] = f2h(scale * src[row * H + j]);
    }
    *(uint4*)dhi = *(const uint4*)thi;
}

// ---- main: 8-wave layer ladder, barrier-synced, four steps per interval,
// single-product f16 matmuls, ONE-STEP-LOOKAHEAD software pipeline:
// two static acc banks; each step's independent input products (wih x
// handoff) + LDS reads are issued BEFORE the previous step's gate burst,
// so the matrix pipe runs underneath the VALU/trans burst.  Serial path
// per step: own-h MFMA -> gates -> pack.
// VALU-balanced wave map: SIMD pairs {L0,L1a} {L2,L1b} {L3,L5a} {L4,L5b}.
__global__ __launch_bounds__(TPB, 2) void gru_mfma(
    const float* __restrict__ x,          // [B][T]
    const float* __restrict__ Wih0,       // [96]
    const float* __restrict__ bih,        // [6][96]
    const float* __restrict__ bhh,        // [6][96]
    const unsigned short* __restrict__ WhFhi,
    const unsigned short* __restrict__ WiFhi,
    const float* __restrict__ Wk, const float* __restrict__ bk,
    const float* __restrict__ We, const float* __restrict__ be,
    const float* __restrict__ Wt, const float* __restrict__ bt,
    float* __restrict__ out, int B)
{
    // handoff slot per (layer 0..4, interval parity, step 0..3), 2 KB each:
    // grp0{hi 1K} grp1{hi 1K}.  row b = 64B; logical 16B-block c stored at
    // column c ^ ((b>>1)&3).
    __shared__ unsigned char slot[5][2][4][2048];   // 80 KB
    __shared__ float xt[T_LEN][BT];
    __shared__ float hpart[L][3][BT];

    const int tid  = threadIdx.x;
    const int wv   = tid >> 6;        // wave index
    const int lane = tid & 63;
    const int b    = lane & 15;       // batch col (MFMA N)
    const int g    = lane >> 4;       // k-group
    const int b0   = blockIdx.x * BT;

    // wave -> (layer, group-mask).  SIMD pairs {w0,w4} {w1,w5} {w2,w6}
    // {w3,w7}; L1 and L5 split in half so every SIMD carries 3 gate-units:
    //   S0:{L0, L1.g0}  S1:{L2, L1.g1}  S2:{L3, L5.g0}  S3:{L4, L5.g1}
    int layer, grmask;
    switch (wv) {
      case 0: layer = 0; grmask = 3; break;   // light scalar-input layer
      case 4: layer = 1; grmask = 1; break;
      case 1: layer = 2; grmask = 3; break;
      case 5: layer = 1; grmask = 2; break;
      case 2: layer = 3; grmask = 3; break;
      case 6: layer = 5; grmask = 1; break;
      case 3: layer = 4; grmask = 3; break;
      default: layer = 5; grmask = 2; break;  // w7
    }

    // stage x tile
    for (int idx = tid; idx < T_LEN * BT; idx += TPB) {
        int bb = idx / T_LEN, t = idx % T_LEN;
        xt[t][bb] = x[(b0 + bb) * T_LEN + t];
    }

    // weight fragments for my layer, held in registers all 100 steps
    f16x8 whh[NT], wih[NT];
#pragma unroll
    for (int t6 = 0; t6 < NT; ++t6)
        whh[t6] = ((const f16x8*)WhFhi)[(layer * NT + t6) * 64 + lane];
    if (layer > 0) {
#pragma unroll
        for (int t6 = 0; t6 < NT; ++t6)
            wih[t6] = ((const f16x8*)WiFhi)[((layer - 1) * NT + t6) * 64 + lane];
    }

    // pre-scaled biases in C/D layout (row = t6*16 + g*4 + r)
    f32x4 bc[4], bxn[2], bhn[2];
    {
        const int rb = g * 4;
#pragma unroll
        for (int t6 = 0; t6 < 4; ++t6)
#pragma unroll
            for (int r = 0; r < 4; ++r) {
                int row = t6 * 16 + rb + r;
                bc[t6][r] = -S1 * (bih[layer * 96 + row] + bhh[layer * 96 + row]);
            }
#pragma unroll
        for (int tt = 0; tt < 2; ++tt)
#pragma unroll
            for (int r = 0; r < 4; ++r) {
                int row = 64 + tt * 16 + rb + r;
                bxn[tt][r] = -2.0f * S1 * bih[layer * 96 + row];
                bhn[tt][r] = -2.0f * S1 * bhh[layer * 96 + row];
            }
        if (layer == 0) {
            // layer-0 wave never uses wih as frags: reuse for pre-scaled f32
            // input weights via the union view
#pragma unroll
            for (int t6 = 0; t6 < NT; ++t6) {
                FragU u;
#pragma unroll
                for (int r = 0; r < 4; ++r) {
                    int row = t6 * 16 + rb + r;
                    float s = (row < 64) ? -S1 : -2.0f * S1;
                    u.f[r] = s * Wih0[row];
                }
                wih[t6] = u.h;
            }
        }
    }

    float hp[2][8];
#pragma unroll
    for (int gr = 0; gr < 2; ++gr)
#pragma unroll
        for (int i = 0; i < 8; ++i) hp[gr][i] = 0.0f;
    f16x8 hfH[2] = {{0,0,0,0,0,0,0,0},{0,0,0,0,0,0,0,0}};

    // unified slot offset (read & write identical): row b, logical block g,
    // XOR-swizzled by (b>>1)&3.  Group gr adds gr*1024.
    const int soff = b * 64 + ((g ^ ((b >> 1) & 3)) << 4);
    unsigned char* const sbase = (unsigned char*)slot;

    // Bank layout A[gr][0..3] = r/z acc, A[gr][4..5] = xn acc (input+bxn),
    // A[gr][6..7] = hn acc (own-h+bhn, set by ownh).

    // fill: input products into a bank (independent of hfH/pack -- only
    // needs last interval's handoff + biases).  C-init = biases.
    auto fill = [&](f32x4 (&A)[2][8], int t, int rq, int st) {
        if (layer > 0) {
            const unsigned char* ru = sbase + (((layer - 1) * 8 + rq * 4 + st) << 11);
            f16x8 iH0, iH1;
            if (grmask & 1) iH0 = *(const f16x8*)(ru + soff);
            if (grmask & 2) iH1 = *(const f16x8*)(ru + 1024 + soff);
            if (grmask & 1) {
#pragma unroll
                for (int t6 = 0; t6 < 4; ++t6)
                    A[0][t6] = __builtin_amdgcn_mfma_f32_16x16x32_f16(wih[t6], iH0, bc[t6], 0, 0, 0);
#pragma unroll
                for (int tt = 0; tt < 2; ++tt)
                    A[0][4 + tt] = __builtin_amdgcn_mfma_f32_16x16x32_f16(wih[4 + tt], iH0, bxn[tt], 0, 0, 0);
            }
            if (grmask & 2) {
#pragma unroll
                for (int t6 = 0; t6 < 4; ++t6)
                    A[1][t6] = __builtin_amdgcn_mfma_f32_16x16x32_f16(wih[t6], iH1, bc[t6], 0, 0, 0);
#pragma unroll
                for (int tt = 0; tt < 2; ++tt)
                    A[1][4 + tt] = __builtin_amdgcn_mfma_f32_16x16x32_f16(wih[4 + tt], iH1, bxn[tt], 0, 0, 0);
            }
        } else {
#pragma unroll
            for (int gr = 0; gr < 2; ++gr)
                if (grmask & (1 << gr)) {
                    float xv = xt[t][gr * 16 + b];
#pragma unroll
                    for (int t6 = 0; t6 < 4; ++t6) {
                        FragU u; u.h = wih[t6];
#pragma unroll
                        for (int r = 0; r < 4; ++r)
                            A[gr][t6][r] = fmaf(u.f[r], xv, bc[t6][r]);
                    }
#pragma unroll
                    for (int tt = 0; tt < 2; ++tt) {
                        FragU u; u.h = wih[4 + tt];
#pragma unroll
                        for (int r = 0; r < 4; ++r)
                            A[gr][4 + tt][r] = fmaf(u.f[r], xv, bxn[tt][r]);
                    }
                }
        }
    };

    // ownh: the serial-path MFMAs -- chain own-h onto r/z tiles, set hn tiles.
    auto ownh = [&](f32x4 (&A)[2][8]) {
#pragma unroll
        for (int gr = 0; gr < 2; ++gr)
            if (grmask & (1 << gr)) {
#pragma unroll
                for (int t6 = 0; t6 < 4; ++t6)
                    A[gr][t6] = __builtin_amdgcn_mfma_f32_16x16x32_f16(whh[t6], hfH[gr], A[gr][t6], 0, 0, 0);
#pragma unroll
                for (int tt = 0; tt < 2; ++tt)
                    A[gr][6 + tt] = __builtin_amdgcn_mfma_f32_16x16x32_f16(whh[4 + tt], hfH[gr], bhn[tt], 0, 0, 0);
            }
    };

    // gates + pack + handoff write.
    // gates (pre-scaled): Er=e^-rpre, Ez=e^-zpre, En=e^-2npre
    // r = 1/(1+Er); n = (1-En)/(1+En); h = [n*Ez + hp] / (1+Ez)
    auto gates = [&](f32x4 (&A)[2][8], int wp, int st) {
#pragma unroll
        for (int gr = 0; gr < 2; ++gr)
            if (grmask & (1 << gr)) {
#pragma unroll
                for (int jj = 0; jj < 2; ++jj)
#pragma unroll
                    for (int r = 0; r < 4; ++r) {
                        float Er = exp2b(A[gr][jj][r]);
                        float Ez = exp2b(A[gr][2 + jj][r]);
                        float rg = rcpa(1.0f + Er);
                        float u  = fmaf(rg, A[gr][6 + jj][r], A[gr][4 + jj][r]);
                        float En = exp2b(u);
                        float en1 = 1.0f + En, ez1 = 1.0f + Ez;
                        float d   = rcpa(en1 * ez1);
                        float t2  = fmaf(-En, Ez, Ez);        // (1-En)*Ez, single-rounded
                        float num = fmaf(hp[gr][jj * 4 + r], en1, t2);
                        hp[gr][jj * 4 + r] = num * d;
                    }
                unsigned int h01 = pk16(hp[gr][0], hp[gr][1]);
                unsigned int h23 = pk16(hp[gr][2], hp[gr][3]);
                unsigned int h45 = pk16(hp[gr][4], hp[gr][5]);
                unsigned int h67 = pk16(hp[gr][6], hp[gr][7]);
                FragU Hu;
                Hu.u[0] = h01; Hu.u[1] = h23; Hu.u[2] = h45; Hu.u[3] = h67;
                hfH[gr] = Hu.h;
                if (layer < L - 1) {
                    unsigned char* wp8 = sbase + ((layer * 8 + wp * 4 + st) << 11) + gr * 1024;
                    *(uint4*)(wp8 + soff) = make_uint4(h01, h23, h45, h67);
                }
            }
    };

    f32x4 A0[2][8], A1[2][8];   // the two pipeline banks (statically indexed)

    __syncthreads();

    for (int i = 0; i < NK; ++i) {
        int k = i - layer;            // local 4-step chunk index
        if (0 <= k && k < NPAIR) {
            const int p = i & 1, q = p ^ 1;
            const int t0 = 4 * k;
            fill(A0, t0 + 0, q, 0);
            ownh(A0); fill(A1, t0 + 1, q, 1); gates(A0, p, 0);
            ownh(A1); fill(A0, t0 + 2, q, 2); gates(A1, p, 1);
            ownh(A0); fill(A1, t0 + 3, q, 3); gates(A0, p, 2);
            ownh(A1);                         gates(A1, p, 3);
        }
        __syncthreads();
    }

    // heads: per-(layer,group) partial over 32 hidden units, then cross-wave reduce
    {
        const int rb = g * 4;
#pragma unroll
        for (int hd = 0; hd < 3; ++hd) {
            const float* W = (hd == 0) ? Wk : (hd == 1) ? We : Wt;
#pragma unroll
            for (int gr = 0; gr < 2; ++gr)
                if (grmask & (1 << gr)) {
                    float s = 0.0f;
#pragma unroll
                    for (int jj = 0; jj < 2; ++jj)
#pragma unroll
                        for (int r = 0; r < 4; ++r)
                            s = fmaf(W[layer * H + jj * 16 + rb + r], hp[gr][jj * 4 + r], s);
                    s += __shfl_xor(s, 16, 64);
                    s += __shfl_xor(s, 32, 64);
                    if (g == 0) hpart[layer][hd][gr * 16 + b] = s;
                }
        }
        __syncthreads();
        if (wv < 3 && lane < BT) {
            int bb = lane;
            float s = (wv == 0) ? bk[0] : (wv == 1) ? be[0] : bt[0];
#pragma unroll
            for (int l = 0; l < L; ++l) s += hpart[l][wv][bb];
            out[wv * B + b0 + bb] = s;
        }
    }
}

extern "C" void kernel_launch(void* const* d_in, const int* in_sizes, int n_in,
                              void* d_out, int out_size, void* d_ws, size_t ws_size,
                              hipStream_t stream)
{
    const float* x    = (const float*)d_in[0];
    const float* Wih0 = (const float*)d_in[1];
    const float* Wih  = (const float*)d_in[2];
    const float* Whh  = (const float*)d_in[3];
    const float* bih  = (const float*)d_in[4];
    const float* bhh  = (const float*)d_in[5];
    const float* Wk   = (const float*)d_in[6];
    const float* bk   = (const float*)d_in[7];
    const float* We   = (const float*)d_in[8];
    const float* be   = (const float*)d_in[9];
    const float* Wt   = (const float*)d_in[10];
    const float* bt   = (const float*)d_in[11];
    float* out = (float*)d_out;

    const int B = in_sizes[0] / T_LEN;   // 16384

    unsigned short* WhFhi = (unsigned short*)d_ws;        // 6*6*64*8 f16
    unsigned short* WiFhi = WhFhi + L * NT * 64 * 8;      // 5*6*64*8 f16

    const int nPack = (L * NT * 64) + ((L - 1) * NT * 64);  // 4224
    pack_frags<<<(nPack + 255) / 256, 256, 0, stream>>>(Whh, Wih, WhFhi, WiFhi);
    gru_mfma<<<B / BT, TPB, 0, stream>>>(x, Wih0, bih, bhh, WhFhi, WiFhi,
                                         Wk, bk, We, be, Wt, bt, out, B);
}